// Round 7
// baseline (249.877 us; speedup 1.0000x reference)
//
#include <hip/hip_runtime.h>

#define HID 64
#define TT  128
#define NROWS 8192
#define NGRP (NROWS / 16)   // 512 groups of 16 length-sorted rows

typedef _Float16 half8 __attribute__((ext_vector_type(8)));
typedef float    f32x4 __attribute__((ext_vector_type(4)));

// d_ws byte layout
#define WS_WF    0        // 12 tiles * 64 lanes * 8 f16  = 12288 B
#define WS_WHH   12288    // 12 * 2kt * 64 * 8 f16        = 24576 B
#define WS_BA    36864    // 128 f32 fused bias r,z
#define WS_BX    37376    // 64 f32 b_f (n input side)
#define WS_BH    37632    // 64 f32 b_hh (n recurrent side)
#define WS_EMB   37888    // 17*8 f16 embedding rows
#define WS_LROW  38176    // 8192 i32 per-row length
#define WS_RANK  70944    // 8192 i32 rank within length bin
#define WS_ORDER 103712   // 8192 i32 rows sorted ascending by L
#define WS_HIST  136480   // 129 i32 histogram -> counting sort

// Fuse input path: W_f = W_ih*W_proj (192x21), b_f = b_ih + W_ih*b_proj.
// Phase 1: 192 threads compute wf rows into LDS + biases + emb table.
// Phase 2: cooperative vectorized emission of MFMA A-layout tiles
//          A[m=lane&15][k=(lane>>4)*8+j], one half8 (16B) store per slot.
__global__ __launch_bounds__(256) void setup_tables(
    const float* __restrict__ E_actor, const float* __restrict__ E_action,
    const float* __restrict__ E_street, const float* __restrict__ W_proj,
    const float* __restrict__ b_proj, const float* __restrict__ W_ih,
    const float* __restrict__ b_ih, const float* __restrict__ W_hh,
    const float* __restrict__ b_hh, char* __restrict__ ws)
{
    _Float16* WF  = (_Float16*)(ws + WS_WF);
    _Float16* WHH = (_Float16*)(ws + WS_WHH);
    float*    BA  = (float*)(ws + WS_BA);
    float*    BX  = (float*)(ws + WS_BX);
    float*    BH  = (float*)(ws + WS_BH);
    _Float16* EMB = (_Float16*)(ws + WS_EMB);

    __shared__ float wfs[192][32];
    const int j = threadIdx.x;

    if (j < 192) {
        float wf[21];
        #pragma unroll
        for (int m = 0; m < 21; m++) wf[m] = 0.f;
        float bf = b_ih[j];
        for (int k = 0; k < 32; k++) {
            float w = W_ih[j * 32 + k];
            bf += w * b_proj[k];
            #pragma unroll
            for (int m = 0; m < 21; m++) wf[m] += w * W_proj[k * 21 + m];
        }
        #pragma unroll
        for (int m = 0; m < 21; m++) wfs[j][m] = wf[m];
        #pragma unroll
        for (int m = 21; m < 32; m++) wfs[j][m] = 0.f;
        if (j < 128) BA[j] = bf + b_hh[j];
        else { BX[j - 128] = bf; BH[j - 128] = b_hh[j]; }
    }
    if (j < 17 * 8) {   // emb rows: 0..6 actor, 7..10 action, 11..15 street, 16 zero
        int r = j >> 3, m = j & 7;
        float v = 0.f;
        if (r < 7)       v = E_actor[r * 8 + m];
        else if (r < 11) v = E_action[(r - 7) * 8 + m];
        else if (r < 16) v = (m < 4) ? E_street[(r - 11) * 4 + m] : 0.f;
        EMB[j] = (_Float16)v;
    }
    __syncthreads();

    // WF: 12 tiles x 64 lanes, one half8 per slot
    for (int idx = j; idx < 12 * 64; idx += 256) {
        const int T = idx >> 6, lane = idx & 63;
        const int g3 = T >> 2, w = T & 3, m16 = lane & 15, kq = lane >> 4;
        const int jr = g3 * 64 + w * 16 + m16;
        _Float16 v[8];
        #pragma unroll
        for (int m = 0; m < 8; m++) v[m] = (_Float16)wfs[jr][kq * 8 + m];
        *(uint4*)&WF[idx * 8] = *(uint4*)v;
    }
    // WHH: 12 tiles x 2 kt x 64 lanes
    for (int idx = j; idx < 12 * 2 * 64; idx += 256) {
        const int T = idx >> 7, rem = idx & 127, kt = rem >> 6, lane = rem & 63;
        const int g3 = T >> 2, w = T & 3, m16 = lane & 15, kq = lane >> 4;
        const int jr = g3 * 64 + w * 16 + m16;
        const int kbase = kt * 32 + kq * 8;
        _Float16 v[8];
        #pragma unroll
        for (int m = 0; m < 8; m++) v[m] = (_Float16)W_hh[jr * HID + kbase + m];
        *(uint4*)&WHH[((T * 2 + kt) * 64 + lane) * 8] = *(uint4*)v;
    }
}

// per-row length via ballot popcount; histogram atomicAdd return = in-bin rank
__global__ __launch_bounds__(256) void len_hist(
    const int* __restrict__ mask, int* __restrict__ Lrow,
    int* __restrict__ Rnk, int* __restrict__ hist)
{
    const int wv = threadIdx.x >> 6, ln = threadIdx.x & 63;
    const int row = blockIdx.x * 4 + wv, base = row * TT;
    const int m0 = mask[base + ln], m1 = mask[base + 64 + ln];
    const int L = __popcll(__ballot(m0 != 0)) + __popcll(__ballot(m1 != 0));
    if (ln == 0) { Lrow[row] = L; Rnk[row] = atomicAdd(&hist[L], 1); }
}

// 129-entry exclusive scan then fully parallel scatter (rank precomputed)
__global__ __launch_bounds__(256) void scan_scatter(
    const int* __restrict__ Lrow, const int* __restrict__ Rnk,
    const int* __restrict__ hist, int* __restrict__ order)
{
    __shared__ int pref[TT + 1];
    const int tid = threadIdx.x;
    if (tid <= TT) pref[tid] = hist[tid];
    __syncthreads();
    if (tid == 0) {
        int run = 0;
        for (int i = 0; i <= TT; i++) { int t = pref[i]; pref[i] = run; run += t; }
    }
    __syncthreads();
    for (int r = tid; r < NROWS; r += 256) order[pref[Lrow[r]] + Rnk[r]] = r;
}

// One 128-thread block (2 waves) per 16-row group. Wave w owns hid-half
// [32w,32w+32) = M-tiles {2w,2w+1} per gate -> 18 MFMA/wave-step. h: f32
// master in regs, f16 LDS copy double-buffered, one 2-wave barrier/step.
// hb stride 72 f16 (36 banks % 32 = 4 -> 2-way = free); pb pad 18 int2.
__global__ __launch_bounds__(128) void gru_mfma(
    const int* __restrict__ actor_ids, const int* __restrict__ action_ids,
    const int* __restrict__ street_ids, const float* __restrict__ bet,
    const char* __restrict__ ws, const int* __restrict__ order,
    const int* __restrict__ Lrow, float* __restrict__ out)
{
    const _Float16* WF  = (const _Float16*)(ws + WS_WF);
    const _Float16* WHH = (const _Float16*)(ws + WS_WHH);
    const float*    BA  = (const float*)(ws + WS_BA);
    const float*    BX  = (const float*)(ws + WS_BX);
    const float*    BH  = (const float*)(ws + WS_BH);
    const _Float16* EMB = (const _Float16*)(ws + WS_EMB);

    __shared__ int2 pb[TT][18];                       // 18432 B, padded
    __shared__ __align__(16) _Float16 hb[2][16][72];  // 4608 B, stride 72
    __shared__ __align__(16) _Float16 embl[144];

    const int tid = threadIdx.x;
    const int wv  = tid >> 6;        // wave = hid half
    const int l   = tid & 63;
    const int q   = l >> 4;          // quad
    const int n   = l & 15;          // batch col within group

    // long/short pairing (groups sorted ascending by L)
    const int b = blockIdx.x;
    const int g = (b & 1) ? (NGRP - 1 - (b >> 1)) : (b >> 1);

    // R6 bug: `if (tid < 136)` with 128 threads left entries 128..135 (the
    // quad-3 zero row) uninitialized -> 0*garbage(inf/NaN) = NaN. Strided fix:
    for (int i = tid; i < 136; i += 128) embl[i] = EMB[i];
    for (int i = tid; i < 2 * 16 * 72 / 2; i += 128) ((int*)hb)[i] = 0;
    {   // stage packed ids+bet: 8 threads per row, 16 t per thread
        const int r = tid >> 3, tl = tid & 7;
        const int rowr = order[g * 16 + r];
        const int base = rowr * TT;
        #pragma unroll
        for (int i = 0; i < 16; i++) {
            const int t = tl + 8 * i;
            const int a = actor_ids[base + t], c = action_ids[base + t];
            const int s = street_ids[base + t];
            const float f = bet[base + t];
            pb[t][r] = make_int2(a | (c << 3) | (s << 5), __float_as_int(f));
        }
    }

    // loop-invariant A-fragments (AGPR-resident is fine for MFMA operands)
    half8 Af[3][2], Ah[3][2][2];
    #pragma unroll
    for (int g3 = 0; g3 < 3; g3++)
        #pragma unroll
        for (int ti = 0; ti < 2; ti++) {
            const int T = g3 * 4 + 2 * wv + ti;
            Af[g3][ti]    = *(const half8*)&WF[(T * 64 + l) * 8];
            Ah[g3][ti][0] = *(const half8*)&WHH[((T * 2 + 0) * 64 + l) * 8];
            Ah[g3][ti][1] = *(const half8*)&WHH[((T * 2 + 1) * 64 + l) * 8];
        }
    f32x4 biasR[2], biasZ[2], biasX[2], biasH[2];
    #pragma unroll
    for (int ti = 0; ti < 2; ti++)
        #pragma unroll
        for (int e = 0; e < 4; e++) {
            const int idx = 16 * (2 * wv + ti) + 4 * q + e;
            biasR[ti][e] = BA[idx];
            biasZ[ti][e] = BA[64 + idx];
            biasX[ti][e] = BX[idx];
            biasH[ti][e] = BH[idx];
        }

    const int myrow = order[g * 16 + n];
    const int Ln    = Lrow[myrow];
    const int Lmax  = __shfl(Ln, 15);   // ascending sort -> n=15 holds max
    const bool isq2 = (q == 2);

    float h[2][4] = {{0.f, 0.f, 0.f, 0.f}, {0.f, 0.f, 0.f, 0.f}};
    __syncthreads();

    for (int t = 0; t < Lmax; t++) {
        const int buf = t & 1;
        const int2 p = pb[t][n];
        const float betv = __int_as_float(p.y);
        const int a = p.x & 7, c = (p.x >> 3) & 3, s = (p.x >> 5) & 7;
        // feats B-frag: quad0 actor, quad1 action, quad2 street+bet, quad3 zero
        const int eidx = (q == 0) ? a : (q == 1) ? (7 + c) : isq2 ? (11 + s) : 16;
        half8 Bf = *(const half8*)&embl[eidx * 8];
        {   // patch bet at k=20 (elements 4,5) on quad2
            uint4* bu = (uint4*)&Bf;
            _Float16 b2[2] = {(_Float16)betv, (_Float16)0.f};
            unsigned bp = *(unsigned*)b2;
            bu->z = isq2 ? bp : bu->z;
        }
        const half8 Bh0 = *(const half8*)&hb[buf][n][q * 8];
        const half8 Bh1 = *(const half8*)&hb[buf][n][32 + q * 8];

        f32x4 aR[2], aZ[2], aH[2], aX[2];
        #pragma unroll
        for (int ti = 0; ti < 2; ti++) {
            // x-side first (independent of hb read -> hides LDS latency)
            aR[ti] = __builtin_amdgcn_mfma_f32_16x16x32_f16(Af[0][ti], Bf, biasR[ti], 0, 0, 0);
            aZ[ti] = __builtin_amdgcn_mfma_f32_16x16x32_f16(Af[1][ti], Bf, biasZ[ti], 0, 0, 0);
            aX[ti] = __builtin_amdgcn_mfma_f32_16x16x32_f16(Af[2][ti], Bf, biasX[ti], 0, 0, 0);
            aR[ti] = __builtin_amdgcn_mfma_f32_16x16x32_f16(Ah[0][ti][0], Bh0, aR[ti], 0, 0, 0);
            aR[ti] = __builtin_amdgcn_mfma_f32_16x16x32_f16(Ah[0][ti][1], Bh1, aR[ti], 0, 0, 0);
            aZ[ti] = __builtin_amdgcn_mfma_f32_16x16x32_f16(Ah[1][ti][0], Bh0, aZ[ti], 0, 0, 0);
            aZ[ti] = __builtin_amdgcn_mfma_f32_16x16x32_f16(Ah[1][ti][1], Bh1, aZ[ti], 0, 0, 0);
            aH[ti] = __builtin_amdgcn_mfma_f32_16x16x32_f16(Ah[2][ti][0], Bh0, biasH[ti], 0, 0, 0);
            aH[ti] = __builtin_amdgcn_mfma_f32_16x16x32_f16(Ah[2][ti][1], Bh1, aH[ti], 0, 0, 0);
        }

        const bool live = (t < Ln);
        #pragma unroll
        for (int ti = 0; ti < 2; ti++) {
            _Float16 hp[4];
            #pragma unroll
            for (int e = 0; e < 4; e++) {
                const float r = __builtin_amdgcn_rcpf(1.f + __expf(-aR[ti][e]));
                const float z = __builtin_amdgcn_rcpf(1.f + __expf(-aZ[ti][e]));
                const float y = aX[ti][e] + r * aH[ti][e];
                const float nn = 1.f - 2.f * __builtin_amdgcn_rcpf(1.f + __expf(2.f * y));
                const float hv = nn + z * (h[ti][e] - nn);
                h[ti][e] = live ? hv : h[ti][e];
                hp[e] = (_Float16)h[ti][e];
            }
            *(uint2*)&hb[buf ^ 1][n][16 * (2 * wv + ti) + 4 * q] = *(uint2*)hp;
        }
        __syncthreads();
    }

    #pragma unroll
    for (int ti = 0; ti < 2; ti++) {
        float4 o = make_float4(h[ti][0], h[ti][1], h[ti][2], h[ti][3]);
        *(float4*)&out[myrow * HID + 16 * (2 * wv + ti) + 4 * q] = o;
    }
}

extern "C" void kernel_launch(void* const* d_in, const int* in_sizes, int n_in,
                              void* d_out, int out_size, void* d_ws, size_t ws_size,
                              hipStream_t stream) {
    const int*   actor_ids  = (const int*)d_in[0];
    const int*   action_ids = (const int*)d_in[1];
    const int*   street_ids = (const int*)d_in[2];
    const float* bet        = (const float*)d_in[3];
    const int*   vmask      = (const int*)d_in[4];
    const float* E_actor    = (const float*)d_in[5];
    const float* E_action   = (const float*)d_in[6];
    const float* E_street   = (const float*)d_in[7];
    const float* W_proj     = (const float*)d_in[8];
    const float* b_proj     = (const float*)d_in[9];
    const float* W_ih       = (const float*)d_in[10];
    const float* W_hh       = (const float*)d_in[11];
    const float* b_ih       = (const float*)d_in[12];
    const float* b_hh       = (const float*)d_in[13];
    float*       out        = (float*)d_out;

    char* ws = (char*)d_ws;
    int*  Lrow  = (int*)(ws + WS_LROW);
    int*  Rnk   = (int*)(ws + WS_RANK);
    int*  order = (int*)(ws + WS_ORDER);
    int*  hist  = (int*)(ws + WS_HIST);

    hipMemsetAsync(hist, 0, (TT + 1) * sizeof(int), stream);
    setup_tables<<<1, 256, 0, stream>>>(E_actor, E_action, E_street, W_proj,
                                        b_proj, W_ih, b_ih, W_hh, b_hh, ws);
    len_hist<<<NROWS / 4, 256, 0, stream>>>(vmask, Lrow, Rnk, hist);
    scan_scatter<<<1, 256, 0, stream>>>(Lrow, Rnk, hist, order);
    gru_mfma<<<NGRP, 128, 0, stream>>>(actor_ids, action_ids, street_ids, bet,
                                       ws, order, Lrow, out);
}

// Round 8
// 185.103 us; speedup vs baseline: 1.3499x; 1.3499x over previous
//
#include <hip/hip_runtime.h>

#define HID 64
#define TT  128
#define NROWS 8192
#define NGRP (NROWS / 16)   // 512 groups of 16 length-sorted rows

typedef _Float16 half8 __attribute__((ext_vector_type(8)));
typedef float    f32x4 __attribute__((ext_vector_type(4)));

// d_ws byte layout
#define WS_WF    0        // 12 tiles * 64 lanes * 8 f16  = 12288 B
#define WS_WHH   12288    // 12 * 2kt * 64 * 8 f16        = 24576 B
#define WS_BA    36864    // 128 f32 fused bias r,z
#define WS_BX    37376    // 64 f32 b_f (n input side)
#define WS_BH    37632    // 64 f32 b_hh (n recurrent side)
#define WS_EMB   37888    // 17*8 f16 embedding rows
#define WS_LROW  38176    // 8192 i32 per-row length
#define WS_ORDER 70944    // 8192 i32 rows sorted ascending by L

// Fused prep: block 0 = weight fusion + MFMA A-tile emission; blocks 1..64 =
// per-row lengths (128 rows each). One dispatch instead of memset+setup+len.
__global__ __launch_bounds__(256) void prep(
    const float* __restrict__ E_actor, const float* __restrict__ E_action,
    const float* __restrict__ E_street, const float* __restrict__ W_proj,
    const float* __restrict__ b_proj, const float* __restrict__ W_ih,
    const float* __restrict__ b_ih, const float* __restrict__ W_hh,
    const float* __restrict__ b_hh, const int* __restrict__ mask,
    char* __restrict__ ws)
{
    const int j = threadIdx.x;
    if (blockIdx.x != 0) {
        // length of 128 rows via ballot popcount of the prefix mask
        int* Lrow = (int*)(ws + WS_LROW);
        const int wv = j >> 6, ln = j & 63;
        const int r0 = (blockIdx.x - 1) * 128;
        for (int i = 0; i < 32; i++) {
            const int row = r0 + i * 4 + wv, base = row * TT;
            const int m0 = mask[base + ln], m1 = mask[base + 64 + ln];
            const int L = __popcll(__ballot(m0 != 0)) + __popcll(__ballot(m1 != 0));
            if (ln == 0) Lrow[row] = L;
        }
        return;
    }

    _Float16* WF  = (_Float16*)(ws + WS_WF);
    _Float16* WHH = (_Float16*)(ws + WS_WHH);
    float*    BA  = (float*)(ws + WS_BA);
    float*    BX  = (float*)(ws + WS_BX);
    float*    BH  = (float*)(ws + WS_BH);
    _Float16* EMB = (_Float16*)(ws + WS_EMB);

    __shared__ float wfs[192][32];
    if (j < 192) {
        // W_f[j][m] = sum_k W_ih[j,k]*W_proj[k,m]; b_f = b_ih + W_ih*b_proj
        float wf[21];
        #pragma unroll
        for (int m = 0; m < 21; m++) wf[m] = 0.f;
        float bf = b_ih[j];
        for (int k = 0; k < 32; k++) {
            float w = W_ih[j * 32 + k];
            bf += w * b_proj[k];
            #pragma unroll
            for (int m = 0; m < 21; m++) wf[m] += w * W_proj[k * 21 + m];
        }
        #pragma unroll
        for (int m = 0; m < 21; m++) wfs[j][m] = wf[m];
        #pragma unroll
        for (int m = 21; m < 32; m++) wfs[j][m] = 0.f;
        if (j < 128) BA[j] = bf + b_hh[j];
        else { BX[j - 128] = bf; BH[j - 128] = b_hh[j]; }
    }
    if (j < 17 * 8) {   // emb rows: 0..6 actor, 7..10 action, 11..15 street, 16 zero
        int r = j >> 3, m = j & 7;
        float v = 0.f;
        if (r < 7)       v = E_actor[r * 8 + m];
        else if (r < 11) v = E_action[(r - 7) * 8 + m];
        else if (r < 16) v = (m < 4) ? E_street[(r - 11) * 4 + m] : 0.f;
        EMB[j] = (_Float16)v;
    }
    __syncthreads();

    // A-layout: A[m=lane&15][k=(lane>>4)*8+pos]
    for (int idx = j; idx < 12 * 64; idx += 256) {
        const int T = idx >> 6, lane = idx & 63;
        const int g3 = T >> 2, w = T & 3, m16 = lane & 15, kq = lane >> 4;
        const int jr = g3 * 64 + w * 16 + m16;
        _Float16 v[8];
        #pragma unroll
        for (int m = 0; m < 8; m++) v[m] = (_Float16)wfs[jr][kq * 8 + m];
        *(uint4*)&WF[idx * 8] = *(uint4*)v;
    }
    for (int idx = j; idx < 12 * 2 * 64; idx += 256) {
        const int T = idx >> 7, rem = idx & 127, kt = rem >> 6, lane = rem & 63;
        const int g3 = T >> 2, w = T & 3, m16 = lane & 15, kq = lane >> 4;
        const int jr = g3 * 64 + w * 16 + m16;
        const int kbase = kt * 32 + kq * 8;
        _Float16 v[8];
        #pragma unroll
        for (int m = 0; m < 8; m++) v[m] = (_Float16)W_hh[jr * HID + kbase + m];
        *(uint4*)&WHH[((T * 2 + kt) * 64 + lane) * 8] = *(uint4*)v;
    }
}

// One block: LDS histogram + register-held ranks + serial 129-scan + scatter.
// (No global histogram, no memset dispatch, no cross-kernel rank traffic.)
__global__ __launch_bounds__(256) void sort_rows(
    const int* __restrict__ Lrow, int* __restrict__ order)
{
    __shared__ int hist[TT + 1];
    __shared__ int pref[TT + 1];
    const int tid = threadIdx.x;
    if (tid <= TT) hist[tid] = 0;
    __syncthreads();
    int rnk[NROWS / 256], Ls[NROWS / 256];
    #pragma unroll 4
    for (int i = 0; i < NROWS / 256; i++) {
        const int r = i * 256 + tid;
        const int L = Lrow[r];
        Ls[i] = L;
        rnk[i] = atomicAdd(&hist[L], 1);
    }
    __syncthreads();
    if (tid == 0) {
        int run = 0;
        for (int i = 0; i <= TT; i++) { pref[i] = run; run += hist[i]; }
    }
    __syncthreads();
    #pragma unroll 4
    for (int i = 0; i < NROWS / 256; i++) {
        const int r = i * 256 + tid;
        order[pref[Ls[i]] + rnk[i]] = r;
    }
}

// One 256-thread block (4 waves) per 16-row group; wave wv owns hid quarter
// [16wv,16wv+16) = M-tiles {wv,4+wv,8+wv}. Per step: 6 h-side MFMA (split-K
// into parallel accumulators, merged by v_add -> dep chain 1 deep) + 3 x-side
// MFMA prefetched for step t+1 (depend only on pre-staged pb -> fill the
// ds_read shadow). fp32 h master in regs, f16 LDS copy double-buffered.
__global__ __launch_bounds__(256, 2) void gru_mfma(
    const int* __restrict__ actor_ids, const int* __restrict__ action_ids,
    const int* __restrict__ street_ids, const float* __restrict__ bet,
    const char* __restrict__ ws, const int* __restrict__ order,
    const int* __restrict__ Lrow, float* __restrict__ out)
{
    const _Float16* WF  = (const _Float16*)(ws + WS_WF);
    const _Float16* WHH = (const _Float16*)(ws + WS_WHH);
    const float*    BA  = (const float*)(ws + WS_BA);
    const float*    BX  = (const float*)(ws + WS_BX);
    const float*    BH  = (const float*)(ws + WS_BH);
    const _Float16* EMB = (const _Float16*)(ws + WS_EMB);

    __shared__ int2 pb[TT][18];                       // padded: write banks spread
    __shared__ __align__(16) _Float16 hb[2][16][72];  // stride 72: 2-way max (free)
    __shared__ __align__(16) _Float16 embl[144];

    const int tid = threadIdx.x;
    const int wv  = tid >> 6;        // wave = hid quarter
    const int l   = tid & 63;
    const int q   = l >> 4;          // quad
    const int n   = l & 15;          // batch col within group

    // long/short pairing (groups sorted ascending by L)
    const int b = blockIdx.x;
    const int g = (b & 1) ? (NGRP - 1 - (b >> 1)) : (b >> 1);

    for (int i = tid; i < 136; i += 256) embl[i] = EMB[i];
    for (int i = tid; i < 2 * 16 * 72 / 2; i += 256) ((int*)hb)[i] = 0;
    {   // stage packed ids+bet: 16 threads per row, 8 t per thread
        const int r = tid >> 4, tl = tid & 15;
        const int rowr = order[g * 16 + r];
        const int base = rowr * TT;
        #pragma unroll
        for (int i = 0; i < 8; i++) {
            const int t = tl + 16 * i;
            const int a = actor_ids[base + t], c = action_ids[base + t];
            const int s = street_ids[base + t];
            const float f = bet[base + t];
            pb[t][r] = make_int2(a | (c << 3) | (s << 5), __float_as_int(f));
        }
    }

    // loop-invariant A-fragments (AGPR-resident is fine for MFMA operands)
    half8 Af[3], Ah[3][2];
    #pragma unroll
    for (int g3 = 0; g3 < 3; g3++) {
        const int T = g3 * 4 + wv;
        Af[g3]    = *(const half8*)&WF[(T * 64 + l) * 8];
        Ah[g3][0] = *(const half8*)&WHH[((T * 2 + 0) * 64 + l) * 8];
        Ah[g3][1] = *(const half8*)&WHH[((T * 2 + 1) * 64 + l) * 8];
    }
    f32x4 biasR, biasZ, biasX, biasH;
    #pragma unroll
    for (int e = 0; e < 4; e++) {
        const int idx = 16 * wv + 4 * q + e;
        biasR[e] = BA[idx];
        biasZ[e] = BA[64 + idx];
        biasX[e] = BX[idx];
        biasH[e] = BH[idx];
    }

    const int myrow = order[g * 16 + n];
    const int Ln    = Lrow[myrow];
    const int Lmax  = __shfl(Ln, 15);   // ascending sort -> n=15 holds max
    const bool isq2 = (q == 2);

    float h[4] = {0.f, 0.f, 0.f, 0.f};
    const f32x4 zero4 = {0.f, 0.f, 0.f, 0.f};

    __syncthreads();   // pb/hb/embl visible

    // prime step-0 x-side accumulators
    f32x4 xR, xZ, xX;
    {
        const int2 p = pb[0][n];
        const int a = p.x & 7, c = (p.x >> 3) & 3, s = (p.x >> 5) & 7;
        const int eidx = (q == 0) ? a : (q == 1) ? (7 + c) : isq2 ? (11 + s) : 16;
        half8 Bf = *(const half8*)&embl[eidx * 8];
        uint4* bu = (uint4*)&Bf;
        _Float16 b2[2] = {(_Float16)__int_as_float(p.y), (_Float16)0.f};
        bu->z = isq2 ? *(unsigned*)b2 : bu->z;
        xR = __builtin_amdgcn_mfma_f32_16x16x32_f16(Af[0], Bf, biasR, 0, 0, 0);
        xZ = __builtin_amdgcn_mfma_f32_16x16x32_f16(Af[1], Bf, biasZ, 0, 0, 0);
        xX = __builtin_amdgcn_mfma_f32_16x16x32_f16(Af[2], Bf, biasX, 0, 0, 0);
    }

    for (int t = 0; t < Lmax; t++) {
        const int buf = t & 1;
        // h-side: split-K parallel accumulators, dep chain = 1 MFMA
        const half8 Bh0 = *(const half8*)&hb[buf][n][q * 8];
        const half8 Bh1 = *(const half8*)&hb[buf][n][32 + q * 8];
        f32x4 aR0 = __builtin_amdgcn_mfma_f32_16x16x32_f16(Ah[0][0], Bh0, xR, 0, 0, 0);
        f32x4 aR1 = __builtin_amdgcn_mfma_f32_16x16x32_f16(Ah[0][1], Bh1, zero4, 0, 0, 0);
        f32x4 aZ0 = __builtin_amdgcn_mfma_f32_16x16x32_f16(Ah[1][0], Bh0, xZ, 0, 0, 0);
        f32x4 aZ1 = __builtin_amdgcn_mfma_f32_16x16x32_f16(Ah[1][1], Bh1, zero4, 0, 0, 0);
        f32x4 aH0 = __builtin_amdgcn_mfma_f32_16x16x32_f16(Ah[2][0], Bh0, biasH, 0, 0, 0);
        f32x4 aH1 = __builtin_amdgcn_mfma_f32_16x16x32_f16(Ah[2][1], Bh1, zero4, 0, 0, 0);
        const f32x4 aXc = xX;

        // prefetch step t+1 x-side (independent of this step's h)
        {
            const int tn = (t + 1 < TT) ? t + 1 : TT - 1;
            const int2 p = pb[tn][n];
            const int a = p.x & 7, c = (p.x >> 3) & 3, s = (p.x >> 5) & 7;
            const int eidx = (q == 0) ? a : (q == 1) ? (7 + c) : isq2 ? (11 + s) : 16;
            half8 Bf = *(const half8*)&embl[eidx * 8];
            uint4* bu = (uint4*)&Bf;
            _Float16 b2[2] = {(_Float16)__int_as_float(p.y), (_Float16)0.f};
            bu->z = isq2 ? *(unsigned*)b2 : bu->z;
            xR = __builtin_amdgcn_mfma_f32_16x16x32_f16(Af[0], Bf, biasR, 0, 0, 0);
            xZ = __builtin_amdgcn_mfma_f32_16x16x32_f16(Af[1], Bf, biasZ, 0, 0, 0);
            xX = __builtin_amdgcn_mfma_f32_16x16x32_f16(Af[2], Bf, biasX, 0, 0, 0);
        }

        const f32x4 aR = aR0 + aR1, aZ = aZ0 + aZ1, aH = aH0 + aH1;
        const bool live = (t < Ln);
        _Float16 hp[4];
        #pragma unroll
        for (int e = 0; e < 4; e++) {
            const float r = __builtin_amdgcn_rcpf(1.f + __expf(-aR[e]));
            const float z = __builtin_amdgcn_rcpf(1.f + __expf(-aZ[e]));
            const float y = aXc[e] + r * aH[e];
            const float nn = 1.f - 2.f * __builtin_amdgcn_rcpf(1.f + __expf(2.f * y));
            const float hv = nn + z * (h[e] - nn);
            h[e] = live ? hv : h[e];
            hp[e] = (_Float16)h[e];
        }
        *(uint2*)&hb[buf ^ 1][n][16 * wv + 4 * q] = *(uint2*)hp;
        __syncthreads();
    }

    float4 o = make_float4(h[0], h[1], h[2], h[3]);
    *(float4*)&out[myrow * HID + 16 * wv + 4 * q] = o;
}

extern "C" void kernel_launch(void* const* d_in, const int* in_sizes, int n_in,
                              void* d_out, int out_size, void* d_ws, size_t ws_size,
                              hipStream_t stream) {
    const int*   actor_ids  = (const int*)d_in[0];
    const int*   action_ids = (const int*)d_in[1];
    const int*   street_ids = (const int*)d_in[2];
    const float* bet        = (const float*)d_in[3];
    const int*   vmask      = (const int*)d_in[4];
    const float* E_actor    = (const float*)d_in[5];
    const float* E_action   = (const float*)d_in[6];
    const float* E_street   = (const float*)d_in[7];
    const float* W_proj     = (const float*)d_in[8];
    const float* b_proj     = (const float*)d_in[9];
    const float* W_ih       = (const float*)d_in[10];
    const float* W_hh       = (const float*)d_in[11];
    const float* b_ih       = (const float*)d_in[12];
    const float* b_hh       = (const float*)d_in[13];
    float*       out        = (float*)d_out;

    char* ws = (char*)d_ws;
    int*  Lrow  = (int*)(ws + WS_LROW);
    int*  order = (int*)(ws + WS_ORDER);

    prep<<<65, 256, 0, stream>>>(E_actor, E_action, E_street, W_proj, b_proj,
                                 W_ih, b_ih, W_hh, b_hh, vmask, ws);
    sort_rows<<<1, 256, 0, stream>>>(Lrow, order);
    gru_mfma<<<NGRP, 256, 0, stream>>>(actor_ids, action_ids, street_ids, bet,
                                       ws, order, Lrow, out);
}

// Round 9
// 183.685 us; speedup vs baseline: 1.3604x; 1.0077x over previous
//
#include <hip/hip_runtime.h>

#define HID 64
#define TT  128
#define NROWS 8192
#define NGRP (NROWS / 16)   // 512 groups of 16 length-sorted rows
#define LOG2E 1.44269504088896f

typedef _Float16 half8 __attribute__((ext_vector_type(8)));
typedef float    f32x4 __attribute__((ext_vector_type(4)));

// d_ws byte layout
#define WS_WF    0        // 12 tiles * 64 lanes * 8 f16  = 12288 B
#define WS_WHH   12288    // 12 * 2kt * 64 * 8 f16        = 24576 B
#define WS_BA    36864    // 128 f32 fused bias r,z (pre-scaled by log2e)
#define WS_BX    37376    // 64 f32 b_f n-side (pre-scaled by 2log2e)
#define WS_BH    37632    // 64 f32 b_hh n-side (pre-scaled by 2log2e)
#define WS_EMB   37888    // 17*8 f16 embedding rows
#define WS_LROW  38176    // 8192 i32 per-row length
#define WS_ORDER 70944    // 8192 i32 rows sorted ascending by L
#define WS_HIST  103712   // 129 i32 (atomics only)
#define WS_PREF  104352   // 129 i32 (atomics only)
#define WS_FLAG  104992   // phase flag (atomics only; ws poison 0xAA != 1,2)
#define WS_DONE  104996   // completion counter (atomics only)

// One dispatch: blocks 0..63 = parallel counting sort of rows by length
// (device-scope atomic phase protocol; 65 blocks all co-resident so spins are
// deadlock-free); block 64 = weight fusion + MFMA A-tile emission.
__global__ __launch_bounds__(256) void sortprep(
    const float* __restrict__ E_actor, const float* __restrict__ E_action,
    const float* __restrict__ E_street, const float* __restrict__ W_proj,
    const float* __restrict__ b_proj, const float* __restrict__ W_ih,
    const float* __restrict__ b_ih, const float* __restrict__ W_hh,
    const float* __restrict__ b_hh, const int* __restrict__ mask,
    char* __restrict__ ws)
{
    const int tid = threadIdx.x;
    const int b   = blockIdx.x;

    if (b == 64) {
        // ---- weight prep (independent of the sort blocks) ----
        _Float16* WF  = (_Float16*)(ws + WS_WF);
        _Float16* WHH = (_Float16*)(ws + WS_WHH);
        float*    BA  = (float*)(ws + WS_BA);
        float*    BX  = (float*)(ws + WS_BX);
        float*    BH  = (float*)(ws + WS_BH);
        _Float16* EMB = (_Float16*)(ws + WS_EMB);
        __shared__ float wfs[192][32];
        const int j = tid;
        if (j < 192) {
            // W_f[j][m] = sum_k W_ih[j,k]*W_proj[k,m]; b_f = b_ih + W_ih*b_proj
            float wf[21];
            #pragma unroll
            for (int m = 0; m < 21; m++) wf[m] = 0.f;
            float bf = b_ih[j];
            for (int k = 0; k < 32; k++) {
                float w = W_ih[j * 32 + k];
                bf += w * b_proj[k];
                #pragma unroll
                for (int m = 0; m < 21; m++) wf[m] += w * W_proj[k * 21 + m];
            }
            // fold log2e (r,z rows) / 2log2e (n rows) into A-side weights so
            // activations use raw v_exp_f32 (=2^x) with no pre-multiplies
            const float s = (j < 128) ? LOG2E : 2.f * LOG2E;
            #pragma unroll
            for (int m = 0; m < 21; m++) wfs[j][m] = wf[m] * s;
            #pragma unroll
            for (int m = 21; m < 32; m++) wfs[j][m] = 0.f;
            if (j < 128) BA[j] = (bf + b_hh[j]) * LOG2E;
            else { BX[j - 128] = bf * 2.f * LOG2E; BH[j - 128] = b_hh[j] * 2.f * LOG2E; }
        }
        if (j < 17 * 8) {   // emb rows: 0..6 actor, 7..10 action, 11..15 street, 16 zero
            int r = j >> 3, m = j & 7;
            float v = 0.f;
            if (r < 7)       v = E_actor[r * 8 + m];
            else if (r < 11) v = E_action[(r - 7) * 8 + m];
            else if (r < 16) v = (m < 4) ? E_street[(r - 11) * 4 + m] : 0.f;
            EMB[j] = (_Float16)v;
        }
        __syncthreads();
        // A-layout: A[m=lane&15][k=(lane>>4)*8+pos]
        for (int idx = j; idx < 12 * 64; idx += 256) {
            const int T = idx >> 6, lane = idx & 63;
            const int g3 = T >> 2, w = T & 3, m16 = lane & 15, kq = lane >> 4;
            const int jr = g3 * 64 + w * 16 + m16;
            _Float16 v[8];
            #pragma unroll
            for (int m = 0; m < 8; m++) v[m] = (_Float16)wfs[jr][kq * 8 + m];
            *(uint4*)&WF[idx * 8] = *(uint4*)v;
        }
        for (int idx = j; idx < 12 * 2 * 64; idx += 256) {
            const int T = idx >> 7, rem = idx & 127, kt = rem >> 6, lane = rem & 63;
            const int g3 = T >> 2, w = T & 3, m16 = lane & 15, kq = lane >> 4;
            const int jr = g3 * 64 + w * 16 + m16;
            const int kbase = kt * 32 + kq * 8;
            const float s = (jr < 128) ? LOG2E : 2.f * LOG2E;
            _Float16 v[8];
            #pragma unroll
            for (int m = 0; m < 8; m++) v[m] = (_Float16)(W_hh[jr * HID + kbase + m] * s);
            *(uint4*)&WHH[((T * 2 + kt) * 64 + lane) * 8] = *(uint4*)v;
        }
        return;
    }

    // ---- parallel counting sort, blocks 0..63 (128 rows each) ----
    int* Lrow  = (int*)(ws + WS_LROW);
    int* order = (int*)(ws + WS_ORDER);
    int* hist  = (int*)(ws + WS_HIST);
    int* pref  = (int*)(ws + WS_PREF);
    int* flag  = (int*)(ws + WS_FLAG);
    int* done  = (int*)(ws + WS_DONE);

    __shared__ int sL[128], sR[128];
    __shared__ int lpref[TT + 1];

    // phase 0: block 0 zeroes hist/done (atomics), then flag=1
    if (b == 0) {
        for (int i = tid; i <= TT; i += 256) atomicExch(&hist[i], 0);
        if (tid == 0) atomicExch(done, 0);
        __syncthreads();           // all zeroing atomics drained
        if (tid == 0) atomicExch(flag, 1);
    } else {
        if (tid == 0) while (atomicAdd(flag, 0) != 1) __builtin_amdgcn_s_sleep(8);
        __syncthreads();
    }

    // phase 1: lengths + global ranks for this block's 128 rows
    const int wv = tid >> 6, ln = tid & 63;
    for (int i = 0; i < 32; i++) {
        const int li  = wv * 32 + i;
        const int row = b * 128 + li;
        const int base = row * TT;
        const int m0 = mask[base + ln], m1 = mask[base + 64 + ln];
        const int L = __popcll(__ballot(m0 != 0)) + __popcll(__ballot(m1 != 0));
        if (ln == 0) {
            Lrow[row] = L;                       // plain store: read next kernel
            sL[li] = L;
            sR[li] = atomicAdd(&hist[L], 1);     // global rank within bin
        }
    }
    __syncthreads();
    if (tid == 0) { __threadfence(); atomicAdd(done, 1); }

    // phase 2: block 0 scans the 129-bin histogram, publishes pref, flag=2
    if (b == 0) {
        if (tid == 0) while (atomicAdd(done, 0) != 64) __builtin_amdgcn_s_sleep(8);
        __syncthreads();
        if (tid <= TT) lpref[tid] = atomicAdd(&hist[tid], 0);
        __syncthreads();
        if (tid == 0) {
            int run = 0;
            for (int i = 0; i <= TT; i++) { int t = lpref[i]; lpref[i] = run; run += t; }
        }
        __syncthreads();
        if (tid <= TT) atomicExch(&pref[tid], lpref[tid]);
        __syncthreads();           // all pref atomics drained
        if (tid == 0) atomicExch(flag, 2);
    } else {
        if (tid == 0) while (atomicAdd(flag, 0) != 2) __builtin_amdgcn_s_sleep(8);
        __syncthreads();
        if (tid <= TT) lpref[tid] = atomicAdd(&pref[tid], 0);
        __syncthreads();
    }

    // phase 3: scatter (plain stores: consumed by the next kernel)
    if (tid < 128) order[lpref[sL[tid]] + sR[tid]] = b * 128 + tid;
}

// One 256-thread block (4 waves) per 16-row group; wave wv owns hid quarter
// [16wv,16wv+16) = M-tiles {wv,4+wv,8+wv}. Per step: 6 h-side MFMA (split-K,
// dep chain 1 deep) + 3 x-side MFMA prefetched for t+1. Weights pre-scaled by
// log2e/2log2e so activations are pure exp2 chains. fp32 h master in regs,
// f16 LDS copy double-buffered. Critical path = Lmax(128) * step-chain.
__global__ __launch_bounds__(256, 2) void gru_mfma(
    const int* __restrict__ actor_ids, const int* __restrict__ action_ids,
    const int* __restrict__ street_ids, const float* __restrict__ bet,
    const char* __restrict__ ws, const int* __restrict__ order,
    const int* __restrict__ Lrow, float* __restrict__ out)
{
    const _Float16* WF  = (const _Float16*)(ws + WS_WF);
    const _Float16* WHH = (const _Float16*)(ws + WS_WHH);
    const float*    BA  = (const float*)(ws + WS_BA);
    const float*    BX  = (const float*)(ws + WS_BX);
    const float*    BH  = (const float*)(ws + WS_BH);
    const _Float16* EMB = (const _Float16*)(ws + WS_EMB);

    __shared__ int2 pb[TT][18];                       // padded: write banks spread
    __shared__ __align__(16) _Float16 hb[2][16][72];  // stride 72: 2-way max (free)
    __shared__ __align__(16) _Float16 embl[144];

    const int tid = threadIdx.x;
    const int wv  = tid >> 6;        // wave = hid quarter
    const int l   = tid & 63;
    const int q   = l >> 4;          // quad
    const int n   = l & 15;          // batch col within group

    const int b = blockIdx.x;
    const int g = (b & 1) ? (NGRP - 1 - (b >> 1)) : (b >> 1);

    for (int i = tid; i < 136; i += 256) embl[i] = EMB[i];
    for (int i = tid; i < 2 * 16 * 72 / 2; i += 256) ((int*)hb)[i] = 0;
    {   // stage packed ids+bet: 16 threads per row, 8 t per thread
        const int r = tid >> 4, tl = tid & 15;
        const int rowr = order[g * 16 + r];
        const int base = rowr * TT;
        #pragma unroll
        for (int i = 0; i < 8; i++) {
            const int t = tl + 16 * i;
            const int a = actor_ids[base + t], c = action_ids[base + t];
            const int s = street_ids[base + t];
            const float f = bet[base + t];
            pb[t][r] = make_int2(a | (c << 3) | (s << 5), __float_as_int(f));
        }
    }

    // loop-invariant A-fragments (AGPR-resident is fine for MFMA operands)
    half8 Af[3], Ah[3][2];
    #pragma unroll
    for (int g3 = 0; g3 < 3; g3++) {
        const int T = g3 * 4 + wv;
        Af[g3]    = *(const half8*)&WF[(T * 64 + l) * 8];
        Ah[g3][0] = *(const half8*)&WHH[((T * 2 + 0) * 64 + l) * 8];
        Ah[g3][1] = *(const half8*)&WHH[((T * 2 + 1) * 64 + l) * 8];
    }
    f32x4 biasR, biasZ, biasX, biasH;
    #pragma unroll
    for (int e = 0; e < 4; e++) {
        const int idx = 16 * wv + 4 * q + e;
        biasR[e] = BA[idx];
        biasZ[e] = BA[64 + idx];
        biasX[e] = BX[idx];
        biasH[e] = BH[idx];
    }

    const int myrow = order[g * 16 + n];
    const int Ln    = Lrow[myrow];
    const int Lmax  = __shfl(Ln, 15);   // ascending sort -> n=15 holds max
    const bool isq2 = (q == 2);

    float h[4] = {0.f, 0.f, 0.f, 0.f};
    const f32x4 zero4 = {0.f, 0.f, 0.f, 0.f};

    __syncthreads();   // pb/hb/embl visible

    // prime step-0 x-side accumulators
    f32x4 xR, xZ, xX;
    {
        const int2 p = pb[0][n];
        const int a = p.x & 7, c = (p.x >> 3) & 3, s = (p.x >> 5) & 7;
        const int eidx = (q == 0) ? a : (q == 1) ? (7 + c) : isq2 ? (11 + s) : 16;
        half8 Bf = *(const half8*)&embl[eidx * 8];
        uint4* bu = (uint4*)&Bf;
        _Float16 b2[2] = {(_Float16)__int_as_float(p.y), (_Float16)0.f};
        bu->z = isq2 ? *(unsigned*)b2 : bu->z;
        xR = __builtin_amdgcn_mfma_f32_16x16x32_f16(Af[0], Bf, biasR, 0, 0, 0);
        xZ = __builtin_amdgcn_mfma_f32_16x16x32_f16(Af[1], Bf, biasZ, 0, 0, 0);
        xX = __builtin_amdgcn_mfma_f32_16x16x32_f16(Af[2], Bf, biasX, 0, 0, 0);
    }

    for (int t = 0; t < Lmax; t++) {
        const int buf = t & 1;
        const half8 Bh0 = *(const half8*)&hb[buf][n][q * 8];
        const half8 Bh1 = *(const half8*)&hb[buf][n][32 + q * 8];
        f32x4 aR0 = __builtin_amdgcn_mfma_f32_16x16x32_f16(Ah[0][0], Bh0, xR, 0, 0, 0);
        f32x4 aR1 = __builtin_amdgcn_mfma_f32_16x16x32_f16(Ah[0][1], Bh1, zero4, 0, 0, 0);
        f32x4 aZ0 = __builtin_amdgcn_mfma_f32_16x16x32_f16(Ah[1][0], Bh0, xZ, 0, 0, 0);
        f32x4 aZ1 = __builtin_amdgcn_mfma_f32_16x16x32_f16(Ah[1][1], Bh1, zero4, 0, 0, 0);
        f32x4 aH0 = __builtin_amdgcn_mfma_f32_16x16x32_f16(Ah[2][0], Bh0, biasH, 0, 0, 0);
        f32x4 aH1 = __builtin_amdgcn_mfma_f32_16x16x32_f16(Ah[2][1], Bh1, zero4, 0, 0, 0);
        const f32x4 aXc = xX;

        // prefetch step t+1 x-side (independent of this step's h)
        {
            const int tn = (t + 1 < TT) ? t + 1 : TT - 1;
            const int2 p = pb[tn][n];
            const int a = p.x & 7, c = (p.x >> 3) & 3, s = (p.x >> 5) & 7;
            const int eidx = (q == 0) ? a : (q == 1) ? (7 + c) : isq2 ? (11 + s) : 16;
            half8 Bf = *(const half8*)&embl[eidx * 8];
            uint4* bu = (uint4*)&Bf;
            _Float16 b2[2] = {(_Float16)__int_as_float(p.y), (_Float16)0.f};
            bu->z = isq2 ? *(unsigned*)b2 : bu->z;
            xR = __builtin_amdgcn_mfma_f32_16x16x32_f16(Af[0], Bf, biasR, 0, 0, 0);
            xZ = __builtin_amdgcn_mfma_f32_16x16x32_f16(Af[1], Bf, biasZ, 0, 0, 0);
            xX = __builtin_amdgcn_mfma_f32_16x16x32_f16(Af[2], Bf, biasX, 0, 0, 0);
        }

        const f32x4 aR = aR0 + aR1, aZ = aZ0 + aZ1, aH = aH0 + aH1;
        const bool live = (t < Ln);
        _Float16 hp[4];
        #pragma unroll
        for (int e = 0; e < 4; e++) {
            // weights pre-scaled: aR,aZ in log2 domain; aX,aH in 2log2e domain
            const float r = __builtin_amdgcn_rcpf(1.f + __builtin_amdgcn_exp2f(-aR[e]));
            const float z = __builtin_amdgcn_rcpf(1.f + __builtin_amdgcn_exp2f(-aZ[e]));
            const float y2 = aXc[e] + r * aH[e];           // = 2*log2e*y
            const float nn = 1.f - 2.f * __builtin_amdgcn_rcpf(1.f + __builtin_amdgcn_exp2f(y2));
            const float hv = nn + z * (h[e] - nn);
            h[e] = live ? hv : h[e];
            hp[e] = (_Float16)h[e];
        }
        *(uint2*)&hb[buf ^ 1][n][16 * wv + 4 * q] = *(uint2*)hp;
        __syncthreads();
    }

    float4 o = make_float4(h[0], h[1], h[2], h[3]);
    *(float4*)&out[myrow * HID + 16 * wv + 4 * q] = o;
}

extern "C" void kernel_launch(void* const* d_in, const int* in_sizes, int n_in,
                              void* d_out, int out_size, void* d_ws, size_t ws_size,
                              hipStream_t stream) {
    const int*   actor_ids  = (const int*)d_in[0];
    const int*   action_ids = (const int*)d_in[1];
    const int*   street_ids = (const int*)d_in[2];
    const float* bet        = (const float*)d_in[3];
    const int*   vmask      = (const int*)d_in[4];
    const float* E_actor    = (const float*)d_in[5];
    const float* E_action   = (const float*)d_in[6];
    const float* E_street   = (const float*)d_in[7];
    const float* W_proj     = (const float*)d_in[8];
    const float* b_proj     = (const float*)d_in[9];
    const float* W_ih       = (const float*)d_in[10];
    const float* W_hh       = (const float*)d_in[11];
    const float* b_ih       = (const float*)d_in[12];
    const float* b_hh       = (const float*)d_in[13];
    float*       out        = (float*)d_out;

    char* ws = (char*)d_ws;
    int*  Lrow  = (int*)(ws + WS_LROW);
    int*  order = (int*)(ws + WS_ORDER);

    sortprep<<<65, 256, 0, stream>>>(E_actor, E_action, E_street, W_proj,
                                     b_proj, W_ih, b_ih, W_hh, b_hh, vmask, ws);
    gru_mfma<<<NGRP, 256, 0, stream>>>(actor_ids, action_ids, street_ids, bet,
                                       ws, order, Lrow, out);
}

// Round 10
// 169.774 us; speedup vs baseline: 1.4718x; 1.0819x over previous
//
#include <hip/hip_runtime.h>

#define HID 64
#define TT  128
#define NROWS 8192
#define NGRP (NROWS / 16)   // 512 groups of 16 rows (natural order)
#define LOG2E 1.44269504088896f

typedef _Float16 half8 __attribute__((ext_vector_type(8)));
typedef float    f32x4 __attribute__((ext_vector_type(4)));

// d_ws byte layout
#define WS_WF    0        // 12 tiles * 64 lanes * 8 f16  = 12288 B
#define WS_WHH   12288    // 12 * 2kt * 64 * 8 f16        = 24576 B
#define WS_BA    36864    // 128 f32 fused bias r,z (pre-scaled by log2e)
#define WS_BX    37376    // 64 f32 b_f n-side (pre-scaled by 2log2e)
#define WS_BH    37632    // 64 f32 b_hh n-side (pre-scaled by 2log2e)
#define WS_EMB   37888    // 17*8 f16 embedding rows

// One small block: weight fusion + MFMA A-tile emission + emb table.
// (R9's 65-block atomic-phase sort kernel cost ~50us and bought zero makespan:
// all 512 gru blocks are co-resident, so makespan = Lmax_global * C with or
// without length sorting. Deleted.)
__global__ __launch_bounds__(256) void prep(
    const float* __restrict__ E_actor, const float* __restrict__ E_action,
    const float* __restrict__ E_street, const float* __restrict__ W_proj,
    const float* __restrict__ b_proj, const float* __restrict__ W_ih,
    const float* __restrict__ b_ih, const float* __restrict__ W_hh,
    const float* __restrict__ b_hh, char* __restrict__ ws)
{
    _Float16* WF  = (_Float16*)(ws + WS_WF);
    _Float16* WHH = (_Float16*)(ws + WS_WHH);
    float*    BA  = (float*)(ws + WS_BA);
    float*    BX  = (float*)(ws + WS_BX);
    float*    BH  = (float*)(ws + WS_BH);
    _Float16* EMB = (_Float16*)(ws + WS_EMB);

    __shared__ float wfs[192][32];
    const int j = threadIdx.x;
    if (j < 192) {
        // W_f[j][m] = sum_k W_ih[j,k]*W_proj[k,m]; b_f = b_ih + W_ih*b_proj
        float wf[21];
        #pragma unroll
        for (int m = 0; m < 21; m++) wf[m] = 0.f;
        float bf = b_ih[j];
        for (int k = 0; k < 32; k++) {
            float w = W_ih[j * 32 + k];
            bf += w * b_proj[k];
            #pragma unroll
            for (int m = 0; m < 21; m++) wf[m] += w * W_proj[k * 21 + m];
        }
        // fold log2e (r,z rows) / 2log2e (n rows) into weights: activations
        // become raw v_exp_f32 (=2^x) chains with no pre-multiplies
        const float s = (j < 128) ? LOG2E : 2.f * LOG2E;
        #pragma unroll
        for (int m = 0; m < 21; m++) wfs[j][m] = wf[m] * s;
        #pragma unroll
        for (int m = 21; m < 32; m++) wfs[j][m] = 0.f;
        if (j < 128) BA[j] = (bf + b_hh[j]) * LOG2E;
        else { BX[j - 128] = bf * 2.f * LOG2E; BH[j - 128] = b_hh[j] * 2.f * LOG2E; }
    }
    if (j < 17 * 8) {   // emb rows: 0..6 actor, 7..10 action, 11..15 street, 16 zero
        int r = j >> 3, m = j & 7;
        float v = 0.f;
        if (r < 7)       v = E_actor[r * 8 + m];
        else if (r < 11) v = E_action[(r - 7) * 8 + m];
        else if (r < 16) v = (m < 4) ? E_street[(r - 11) * 4 + m] : 0.f;
        EMB[j] = (_Float16)v;
    }
    __syncthreads();

    // A-layout: A[m=lane&15][k=(lane>>4)*8+pos]
    for (int idx = j; idx < 12 * 64; idx += 256) {
        const int T = idx >> 6, lane = idx & 63;
        const int g3 = T >> 2, w = T & 3, m16 = lane & 15, kq = lane >> 4;
        const int jr = g3 * 64 + w * 16 + m16;
        _Float16 v[8];
        #pragma unroll
        for (int m = 0; m < 8; m++) v[m] = (_Float16)wfs[jr][kq * 8 + m];
        *(uint4*)&WF[idx * 8] = *(uint4*)v;
    }
    for (int idx = j; idx < 12 * 2 * 64; idx += 256) {
        const int T = idx >> 7, rem = idx & 127, kt = rem >> 6, lane = rem & 63;
        const int g3 = T >> 2, w = T & 3, m16 = lane & 15, kq = lane >> 4;
        const int jr = g3 * 64 + w * 16 + m16;
        const int kbase = kt * 32 + kq * 8;
        const float s = (jr < 128) ? LOG2E : 2.f * LOG2E;
        _Float16 v[8];
        #pragma unroll
        for (int m = 0; m < 8; m++) v[m] = (_Float16)(W_hh[jr * HID + kbase + m] * s);
        *(uint4*)&WHH[((T * 2 + kt) * 64 + lane) * 8] = *(uint4*)v;
    }
}

// One 256-thread block (4 waves) per 16-row group (natural order); wave wv
// owns hid quarter [16wv,16wv+16) = M-tiles {wv,4+wv,8+wv}. Per step: 6
// h-side MFMA (split-K, dep chain 1 deep) + 3 x-side MFMA prefetched for t+1.
// Row lengths computed in-kernel from the prefix mask (partial popcounts
// during pb staging). pb packed to one int: ids | bet_f16 << 16.
__global__ __launch_bounds__(256, 2) void gru_mfma(
    const int* __restrict__ actor_ids, const int* __restrict__ action_ids,
    const int* __restrict__ street_ids, const float* __restrict__ bet,
    const int* __restrict__ mask, const char* __restrict__ ws,
    float* __restrict__ out)
{
    const _Float16* WF  = (const _Float16*)(ws + WS_WF);
    const _Float16* WHH = (const _Float16*)(ws + WS_WHH);
    const float*    BA  = (const float*)(ws + WS_BA);
    const float*    BX  = (const float*)(ws + WS_BX);
    const float*    BH  = (const float*)(ws + WS_BH);
    const _Float16* EMB = (const _Float16*)(ws + WS_EMB);

    __shared__ int pb[TT][17];                        // ids|bet16, padded
    __shared__ __align__(16) _Float16 hb[2][16][72];  // stride 72: 2-way max (free)
    __shared__ __align__(16) _Float16 embl[144];
    __shared__ int part[16][16];                      // mask popcount partials
    __shared__ int Lsh[16];

    const int tid = threadIdx.x;
    const int wv  = tid >> 6;        // wave = hid quarter
    const int l   = tid & 63;
    const int q   = l >> 4;          // quad
    const int n   = l & 15;          // batch col within group

    const int g = blockIdx.x;

    for (int i = tid; i < 136; i += 256) embl[i] = EMB[i];
    for (int i = tid; i < 2 * 16 * 72 / 2; i += 256) ((int*)hb)[i] = 0;
    {   // stage packed ids+bet16 + mask partial popcounts: 16 thr/row, 8 t/thr
        const int r = tid >> 4, tl = tid & 15;
        const int base = (g * 16 + r) * TT;
        int cnt = 0;
        #pragma unroll
        for (int i = 0; i < 8; i++) {
            const int t = tl + 16 * i;
            const int a = actor_ids[base + t], c = action_ids[base + t];
            const int s = street_ids[base + t];
            const _Float16 f16 = (_Float16)bet[base + t];
            const unsigned fb = (unsigned)*(const unsigned short*)&f16;
            pb[t][r] = (int)(a | (c << 3) | (s << 5) | (fb << 16));
            cnt += (mask[base + t] != 0);
        }
        part[r][tl] = cnt;
    }

    // loop-invariant A-fragments (AGPR-resident is fine for MFMA operands)
    half8 Af[3], Ah[3][2];
    #pragma unroll
    for (int g3 = 0; g3 < 3; g3++) {
        const int T = g3 * 4 + wv;
        Af[g3]    = *(const half8*)&WF[(T * 64 + l) * 8];
        Ah[g3][0] = *(const half8*)&WHH[((T * 2 + 0) * 64 + l) * 8];
        Ah[g3][1] = *(const half8*)&WHH[((T * 2 + 1) * 64 + l) * 8];
    }
    f32x4 biasR, biasZ, biasX, biasH;
    #pragma unroll
    for (int e = 0; e < 4; e++) {
        const int idx = 16 * wv + 4 * q + e;
        biasR[e] = BA[idx];
        biasZ[e] = BA[64 + idx];
        biasX[e] = BX[idx];
        biasH[e] = BH[idx];
    }

    __syncthreads();   // pb/hb/embl/part visible
    if (tid < 16) {    // row length = popcount of prefix mask
        int L = 0;
        #pragma unroll
        for (int i = 0; i < 16; i++) L += part[tid][i];
        Lsh[tid] = L;
    }
    __syncthreads();

    const int Ln = Lsh[n];
    int Lmax = Ln;     // butterfly max over the 16 n-columns (wave-uniform)
    #pragma unroll
    for (int k = 1; k < 16; k <<= 1) {
        const int o = __shfl_xor(Lmax, k);
        Lmax = (o > Lmax) ? o : Lmax;
    }

    const bool isq2 = (q == 2);
    float h[4] = {0.f, 0.f, 0.f, 0.f};
    const f32x4 zero4 = {0.f, 0.f, 0.f, 0.f};

    // prime step-0 x-side accumulators
    f32x4 xR, xZ, xX;
    {
        const int p = pb[0][n];
        const int a = p & 7, c = (p >> 3) & 3, s = (p >> 5) & 7;
        const int eidx = (q == 0) ? a : (q == 1) ? (7 + c) : isq2 ? (11 + s) : 16;
        half8 Bf = *(const half8*)&embl[eidx * 8];
        uint4* bu = (uint4*)&Bf;
        bu->z = isq2 ? ((unsigned)p >> 16) : bu->z;   // {bet16, 0} at k=20,21
        xR = __builtin_amdgcn_mfma_f32_16x16x32_f16(Af[0], Bf, biasR, 0, 0, 0);
        xZ = __builtin_amdgcn_mfma_f32_16x16x32_f16(Af[1], Bf, biasZ, 0, 0, 0);
        xX = __builtin_amdgcn_mfma_f32_16x16x32_f16(Af[2], Bf, biasX, 0, 0, 0);
    }

    for (int t = 0; t < Lmax; t++) {
        const int buf = t & 1;
        const half8 Bh0 = *(const half8*)&hb[buf][n][q * 8];
        const half8 Bh1 = *(const half8*)&hb[buf][n][32 + q * 8];
        f32x4 aR0 = __builtin_amdgcn_mfma_f32_16x16x32_f16(Ah[0][0], Bh0, xR, 0, 0, 0);
        f32x4 aR1 = __builtin_amdgcn_mfma_f32_16x16x32_f16(Ah[0][1], Bh1, zero4, 0, 0, 0);
        f32x4 aZ0 = __builtin_amdgcn_mfma_f32_16x16x32_f16(Ah[1][0], Bh0, xZ, 0, 0, 0);
        f32x4 aZ1 = __builtin_amdgcn_mfma_f32_16x16x32_f16(Ah[1][1], Bh1, zero4, 0, 0, 0);
        f32x4 aH0 = __builtin_amdgcn_mfma_f32_16x16x32_f16(Ah[2][0], Bh0, biasH, 0, 0, 0);
        f32x4 aH1 = __builtin_amdgcn_mfma_f32_16x16x32_f16(Ah[2][1], Bh1, zero4, 0, 0, 0);
        const f32x4 aXc = xX;

        // prefetch step t+1 x-side (independent of this step's h)
        {
            const int tn = (t + 1 < TT) ? t + 1 : TT - 1;
            const int p = pb[tn][n];
            const int a = p & 7, c = (p >> 3) & 3, s = (p >> 5) & 7;
            const int eidx = (q == 0) ? a : (q == 1) ? (7 + c) : isq2 ? (11 + s) : 16;
            half8 Bf = *(const half8*)&embl[eidx * 8];
            uint4* bu = (uint4*)&Bf;
            bu->z = isq2 ? ((unsigned)p >> 16) : bu->z;
            xR = __builtin_amdgcn_mfma_f32_16x16x32_f16(Af[0], Bf, biasR, 0, 0, 0);
            xZ = __builtin_amdgcn_mfma_f32_16x16x32_f16(Af[1], Bf, biasZ, 0, 0, 0);
            xX = __builtin_amdgcn_mfma_f32_16x16x32_f16(Af[2], Bf, biasX, 0, 0, 0);
        }

        const f32x4 aR = aR0 + aR1, aZ = aZ0 + aZ1, aH = aH0 + aH1;
        const bool live = (t < Ln);
        _Float16 hp[4];
        #pragma unroll
        for (int e = 0; e < 4; e++) {
            // weights pre-scaled: aR,aZ in log2 domain; aX,aH in 2log2e domain
            const float r = __builtin_amdgcn_rcpf(1.f + __builtin_amdgcn_exp2f(-aR[e]));
            const float z = __builtin_amdgcn_rcpf(1.f + __builtin_amdgcn_exp2f(-aZ[e]));
            const float y2 = aXc[e] + r * aH[e];           // = 2*log2e*y
            const float nn = 1.f - 2.f * __builtin_amdgcn_rcpf(1.f + __builtin_amdgcn_exp2f(y2));
            const float hv = nn + z * (h[e] - nn);
            h[e] = live ? hv : h[e];
            hp[e] = (_Float16)h[e];
        }
        *(uint2*)&hb[buf ^ 1][n][16 * wv + 4 * q] = *(uint2*)hp;
        __syncthreads();
    }

    float4 o = make_float4(h[0], h[1], h[2], h[3]);
    *(float4*)&out[(g * 16 + n) * HID + 16 * wv + 4 * q] = o;
}

extern "C" void kernel_launch(void* const* d_in, const int* in_sizes, int n_in,
                              void* d_out, int out_size, void* d_ws, size_t ws_size,
                              hipStream_t stream) {
    const int*   actor_ids  = (const int*)d_in[0];
    const int*   action_ids = (const int*)d_in[1];
    const int*   street_ids = (const int*)d_in[2];
    const float* bet        = (const float*)d_in[3];
    const int*   vmask      = (const int*)d_in[4];
    const float* E_actor    = (const float*)d_in[5];
    const float* E_action   = (const float*)d_in[6];
    const float* E_street   = (const float*)d_in[7];
    const float* W_proj     = (const float*)d_in[8];
    const float* b_proj     = (const float*)d_in[9];
    const float* W_ih       = (const float*)d_in[10];
    const float* W_hh       = (const float*)d_in[11];
    const float* b_ih       = (const float*)d_in[12];
    const float* b_hh       = (const float*)d_in[13];
    float*       out        = (float*)d_out;

    char* ws = (char*)d_ws;
    prep<<<1, 256, 0, stream>>>(E_actor, E_action, E_street, W_proj, b_proj,
                                W_ih, b_ih, W_hh, b_hh, ws);
    gru_mfma<<<NGRP, 256, 0, stream>>>(actor_ids, action_ids, street_ids, bet,
                                       vmask, ws, out);
}